// Round 1
// baseline (46.339 us; speedup 1.0000x reference)
//
#include <hip/hip_runtime.h>

#define THREADS 256
#define BLOCKS 2048   // 256 CUs * 8 blocks/CU; grid-stride handles the rest

__global__ __launch_bounds__(THREADS) void sum_stage1(
    const float4* __restrict__ x, float* __restrict__ partials, int n4) {
    float s = 0.0f;
    for (int i = blockIdx.x * blockDim.x + threadIdx.x; i < n4;
         i += gridDim.x * blockDim.x) {
        float4 v = x[i];
        s += (v.x + v.y) + (v.z + v.w);
    }
    // wave-64 butterfly reduce
    #pragma unroll
    for (int off = 32; off > 0; off >>= 1)
        s += __shfl_down(s, off, 64);
    __shared__ float lds[THREADS / 64];
    const int lane = threadIdx.x & 63;
    const int wave = threadIdx.x >> 6;
    if (lane == 0) lds[wave] = s;
    __syncthreads();
    if (threadIdx.x == 0) {
        float t = 0.0f;
        #pragma unroll
        for (int w = 0; w < THREADS / 64; ++w) t += lds[w];
        partials[blockIdx.x] = t;
    }
}

__global__ __launch_bounds__(THREADS) void sum_stage2(
    const float* __restrict__ partials, float* __restrict__ out, int n) {
    float s = 0.0f;
    for (int i = threadIdx.x; i < n; i += blockDim.x) s += partials[i];
    #pragma unroll
    for (int off = 32; off > 0; off >>= 1)
        s += __shfl_down(s, off, 64);
    __shared__ float lds[THREADS / 64];
    const int lane = threadIdx.x & 63;
    const int wave = threadIdx.x >> 6;
    if (lane == 0) lds[wave] = s;
    __syncthreads();
    if (threadIdx.x == 0) {
        float t = 0.0f;
        #pragma unroll
        for (int w = 0; w < THREADS / 64; ++w) t += lds[w];
        out[0] = t;
    }
}

extern "C" void kernel_launch(void* const* d_in, const int* in_sizes, int n_in,
                              void* d_out, int out_size, void* d_ws, size_t ws_size,
                              hipStream_t stream) {
    const float* x = (const float*)d_in[0];
    float* out = (float*)d_out;
    float* partials = (float*)d_ws;   // BLOCKS floats = 8 KiB scratch

    const int n = in_sizes[0];        // 64*1024*1024, divisible by 4
    const int n4 = n / 4;

    sum_stage1<<<BLOCKS, THREADS, 0, stream>>>((const float4*)x, partials, n4);
    sum_stage2<<<1, THREADS, 0, stream>>>(partials, out, BLOCKS);
}